// Round 4
// baseline (242.577 us; speedup 1.0000x reference)
//
#include <hip/hip_runtime.h>
#include <hip/hip_bf16.h>

// Problem dims (fixed by reference setup_inputs)
#define M_DIM 32
#define K_DIM 8192
#define N_DIM 8192
#define KS 16                       // k-split slices
#define KCH (K_DIM / KS)            // 512 k per block
#define CHK 128                     // k per LDS chunk
#define NCHK (KCH / CHK)            // 4 chunks per block
#define STEPS (CHK / 32)            // 4 MFMA k-steps per chunk
#define NPB 128                     // n-cols per block (4 waves x 32)
#define NBLK (N_DIM / NPB)          // 64
#define MAIN_BLOCKS (NBLK * KS)     // 1024

#define QW_ROW (K_DIM / 8)          // 1024 int4 per qweight row
#define SC_ROW (K_DIM / 16)         // 512 f32 per scales row

// LDS row strides (padded: fragment gathers are ~2-way on banks = free)
#define QROW 17                     // int4 per Q row (16 data + 1 pad)
#define AROW 136                    // f16 per A row (128 + 8 pad)
#define SROW 9                      // f32 per S row (8 + 1 pad)

typedef _Float16 half8   __attribute__((ext_vector_type(8)));
typedef _Float16 half4_t __attribute__((ext_vector_type(4)));
typedef _Float16 half2_t __attribute__((ext_vector_type(2)));
typedef float    floatx4 __attribute__((ext_vector_type(4)));

#if defined(__has_builtin)
#if __has_builtin(__builtin_amdgcn_cvt_scalef32_pk_f16_fp4)
#define HAVE_CVT_FP4 1
#endif
#endif

#ifndef HAVE_CVT_FP4
// Manual E2M1 decode fallback: mag code m -> f16 bits t<<9,
// t = min(28m, m+28) = [0,28,30,31,32,33,34,35]; sign bit3 -> bit15.
__device__ __forceinline__ uint32_t dec2(uint32_t q) {
  uint32_t c0 = q & 0xFu, c1 = (q >> 4) & 0xFu;
  uint32_t m0 = c0 & 7u, m1 = c1 & 7u;
  uint32_t t0 = min(28u * m0, m0 + 28u);
  uint32_t t1 = min(28u * m1, m1 + 28u);
  return (t0 << 9) | ((c0 & 8u) << 12)
       | (t1 << 25) | ((c1 & 8u) << 28);
}
#endif

// 4 dwords (1 payload byte each = 2 fp4) -> 8 f16 * scale.
__device__ __forceinline__ half8 decode8(int4 q, float scale) {
  union { uint32_t u[4]; half2_t h2[4]; half8 h; } w;
#ifdef HAVE_CVT_FP4
  w.h2[0] = __builtin_amdgcn_cvt_scalef32_pk_f16_fp4((unsigned)q.x, 1.0f, 0);
  w.h2[1] = __builtin_amdgcn_cvt_scalef32_pk_f16_fp4((unsigned)q.y, 1.0f, 0);
  w.h2[2] = __builtin_amdgcn_cvt_scalef32_pk_f16_fp4((unsigned)q.z, 1.0f, 0);
  w.h2[3] = __builtin_amdgcn_cvt_scalef32_pk_f16_fp4((unsigned)q.w, 1.0f, 0);
#else
  w.u[0] = dec2((uint32_t)q.x);
  w.u[1] = dec2((uint32_t)q.y);
  w.u[2] = dec2((uint32_t)q.z);
  w.u[3] = dec2((uint32_t)q.w);
#endif
  _Float16 s = (_Float16)scale;
  half8 sv = {s, s, s, s, s, s, s, s};
  return w.h * sv;
}

// out[m][n] = bias[n] (atomic-fallback path only)
__global__ void init_out_kernel(floatx4* __restrict__ out4,
                                const floatx4* __restrict__ bias4) {
  int idx = blockIdx.x * blockDim.x + threadIdx.x;
  out4[idx] = bias4[idx & (N_DIM / 4 - 1)];
}

// out = bias + sum over KS partial slabs (partial path)
__global__ void reduce_kernel(const floatx4* __restrict__ part,
                              const floatx4* __restrict__ bias4,
                              floatx4* __restrict__ out4) {
  int idx = blockIdx.x * blockDim.x + threadIdx.x;   // [0, 65536)
  floatx4 acc = bias4[idx & (N_DIM / 4 - 1)];
#pragma unroll
  for (int s = 0; s < KS; ++s)
    acc += part[(size_t)s * (M_DIM * N_DIM / 4) + idx];
  out4[idx] = acc;
}

template <bool PARTIAL>
__global__ __launch_bounds__(256, 3) void fp4_linear_kernel(
    const float* __restrict__ inp,     // [32, 8192] f32
    const int4*  __restrict__ qw4,     // [N][1024] int4 view of [N, K/2] i32
    const float* __restrict__ scales,  // [8192, 512] f32
    const float* __restrict__ amaxp,   // [1]
    float* __restrict__ outp)          // PARTIAL: ws [KS][32][8192]; else out
{
  __shared__ int4     Qs[NPB * QROW];      // 34816 B
  __shared__ _Float16 As[M_DIM * AROW];    //  8704 B
  __shared__ float    Ss[NPB * SROW];      //  4608 B

  const int t    = threadIdx.x;
  const int lane = t & 63;
  const int w    = t >> 6;
  const int ks   = blockIdx.x & (KS - 1);
  const int nb   = blockIdx.x >> 4;        // log2(KS) = 4
  const int n0   = nb * NPB;
  const int kb   = ks * KCH;
  const float amax = amaxp[0];

  // Register staging buffers: 13 independent global loads in flight.
  int4    qreg[8];
  floatx4 areg[4];
  floatx4 sreg;

  // Bulk, contiguous loads. Per instruction: 64 lanes cover
  //   Q: 4 rows x 256 B contiguous;  A: 2 rows x 512 B;  S: 128 rows x 64 B.
  auto load_chunk = [&](int kc) {
    const int4* qbase = qw4 + (kc >> 3);
#pragma unroll
    for (int p = 0; p < 8; ++p) {
      const int r = p * 16 + (t >> 4);
      qreg[p] = qbase[(size_t)(n0 + r) * QW_ROW + (t & 15)];
    }
    const float* abase = inp + kc;
#pragma unroll
    for (int p = 0; p < 4; ++p) {
      const int r = p * 8 + (t >> 5);
      areg[p] = ((const floatx4*)(abase + (size_t)r * K_DIM))[t & 31];
    }
    sreg = ((const floatx4*)(scales + (size_t)(n0 + (t >> 1)) * SC_ROW
                             + (kc >> 4)))[t & 1];
  };

  auto store_chunk = [&]() {
#pragma unroll
    for (int p = 0; p < 8; ++p)
      Qs[(p * 16 + (t >> 4)) * QROW + (t & 15)] = qreg[p];
#pragma unroll
    for (int p = 0; p < 4; ++p) {
      floatx4 f = areg[p];
      half4_t h;
      h[0] = (_Float16)f[0]; h[1] = (_Float16)f[1];
      h[2] = (_Float16)f[2]; h[3] = (_Float16)f[3];
      *(half4_t*)&As[(p * 8 + (t >> 5)) * AROW + (t & 31) * 4] = h;
    }
    float* sd = &Ss[(t >> 1) * SROW + (t & 1) * 4];
    sd[0] = sreg[0] * amax; sd[1] = sreg[1] * amax;
    sd[2] = sreg[2] * amax; sd[3] = sreg[3] * amax;
  };

  const int row  = lane & 15;   // n-within-tile (B) / m-within-tile (A)
  const int quad = lane >> 4;   // which 8 k's of the 32-k MFMA step
  const int nloc = w * 32;

  floatx4 acc00 = {0.f, 0.f, 0.f, 0.f};
  floatx4 acc01 = {0.f, 0.f, 0.f, 0.f};
  floatx4 acc10 = {0.f, 0.f, 0.f, 0.f};
  floatx4 acc11 = {0.f, 0.f, 0.f, 0.f};

  const int4*     qApt = &Qs[(nloc + row) * QROW];
  const int4*     qBpt = &Qs[(nloc + 16 + row) * QROW];
  const _Float16* a0pt = &As[row * AROW];
  const _Float16* a1pt = &As[(row + 16) * AROW];
  const float*    sApt = &Ss[(nloc + row) * SROW];
  const float*    sBpt = &Ss[(nloc + 16 + row) * SROW];

  load_chunk(kb);
  for (int c = 0; c < NCHK; ++c) {
    if (c) __syncthreads();          // LDS of chunk c-1 fully consumed
    store_chunk();
    __syncthreads();
    if (c + 1 < NCHK) load_chunk(kb + (c + 1) * CHK);  // overlap with MFMA

#pragma unroll
    for (int it = 0; it < STEPS; ++it) {
      const int qi  = it * 4 + quad;
      const int kbl = it * 2 + (quad >> 1);
      const int klo = it * 32 + quad * 8;
      half8 bA = decode8(qApt[qi], sApt[kbl]);
      half8 bB = decode8(qBpt[qi], sBpt[kbl]);
      half8 a0 = *(const half8*)(a0pt + klo);
      half8 a1 = *(const half8*)(a1pt + klo);
      acc00 = __builtin_amdgcn_mfma_f32_16x16x32_f16(a0, bA, acc00, 0, 0, 0);
      acc01 = __builtin_amdgcn_mfma_f32_16x16x32_f16(a0, bB, acc01, 0, 0, 0);
      acc10 = __builtin_amdgcn_mfma_f32_16x16x32_f16(a1, bA, acc10, 0, 0, 0);
      acc11 = __builtin_amdgcn_mfma_f32_16x16x32_f16(a1, bB, acc11, 0, 0, 0);
    }
  }

  // Epilogue. D layout: col(n) = lane&15, row(m) = quad*4 + reg (verified R1).
  if (PARTIAL) {
    float* pb = outp + (size_t)ks * (M_DIM * N_DIM);
#pragma unroll
    for (int r = 0; r < 4; ++r) {
      const int m = quad * 4 + r;
      float* o0 = pb + (size_t)m * N_DIM + n0 + nloc;
      float* o1 = pb + (size_t)(m + 16) * N_DIM + n0 + nloc;
      o0[row]      = acc00[r];
      o0[16 + row] = acc01[r];
      o1[row]      = acc10[r];
      o1[16 + row] = acc11[r];
    }
  } else {
#pragma unroll
    for (int r = 0; r < 4; ++r) {
      const int m = quad * 4 + r;
      float* o0 = outp + (size_t)m * N_DIM + n0 + nloc;
      float* o1 = outp + (size_t)(m + 16) * N_DIM + n0 + nloc;
      unsafeAtomicAdd(o0 + row,      acc00[r]);
      unsafeAtomicAdd(o0 + 16 + row, acc01[r]);
      unsafeAtomicAdd(o1 + row,      acc10[r]);
      unsafeAtomicAdd(o1 + 16 + row, acc11[r]);
    }
  }
}

extern "C" void kernel_launch(void* const* d_in, const int* in_sizes, int n_in,
                              void* d_out, int out_size, void* d_ws, size_t ws_size,
                              hipStream_t stream) {
  const float* inp    = (const float*)d_in[0];
  const int4*  qw4    = (const int4*)d_in[1];
  const float* scales = (const float*)d_in[2];
  const float* amaxp  = (const float*)d_in[3];
  const float* bias   = (const float*)d_in[4];
  float* out = (float*)d_out;

  const size_t part_bytes = (size_t)KS * M_DIM * N_DIM * sizeof(float);  // 16 MB
  if (ws_size >= part_bytes) {
    float* part = (float*)d_ws;
    fp4_linear_kernel<true><<<MAIN_BLOCKS, 256, 0, stream>>>(
        inp, qw4, scales, amaxp, part);
    reduce_kernel<<<M_DIM * N_DIM / 4 / 256, 256, 0, stream>>>(
        (const floatx4*)part, (const floatx4*)bias, (floatx4*)out);
  } else {
    init_out_kernel<<<M_DIM * N_DIM / 4 / 256, 256, 0, stream>>>(
        (floatx4*)out, (const floatx4*)bias);
    fp4_linear_kernel<false><<<MAIN_BLOCKS, 256, 0, stream>>>(
        inp, qw4, scales, amaxp, out);
  }
}

// Round 6
// 224.417 us; speedup vs baseline: 1.0809x; 1.0809x over previous
//
#include <hip/hip_runtime.h>
#include <hip/hip_bf16.h>

// Problem dims (fixed by reference setup_inputs)
#define M_DIM 32
#define K_DIM 8192
#define N_DIM 8192
#define KS 16                       // k-split slices
#define KCH (K_DIM / KS)            // 512 k per block slice
#define STEPS (KCH / 32)            // 16 MFMA k-steps
#define NPB 128                     // n-cols per block (4 waves x 32)
#define NBLK (N_DIM / NPB)          // 64
#define MAIN_BLOCKS (NBLK * KS)     // 1024

#define QW_ROWI4 (K_DIM / 8)        // 1024 int4 per qweight row
#define SC_ROW (K_DIM / 16)         // 512 f32 per scales row

// LDS layouts (padded; read-side conflicts <=2-way = free)
#define QROW 65                     // packed dwords per Q row (64 + 1 pad)
#define AROW 520                    // f16 per A row (512 + 8 pad)
#define SROW 34                     // f16 per S row (32 + 2 pad)

typedef _Float16 half8   __attribute__((ext_vector_type(8)));
typedef _Float16 half4_t __attribute__((ext_vector_type(4)));
typedef float    floatx4 __attribute__((ext_vector_type(4)));

// ---- Proven E2M1 bit-decode (R1 pedigree, absmax 2.0) ----
// One byte = 2 fp4 (low nibble = even k). mag code m -> f16 bits t<<9,
// t = min(28m, m+28) = [0,28,30,31,32,33,34,35]; sign bit3 -> bit15.
__device__ __forceinline__ uint32_t dec2(uint32_t b) {
  uint32_t c0 = b & 0xFu, c1 = (b >> 4) & 0xFu;
  uint32_t m0 = c0 & 7u, m1 = c1 & 7u;
  uint32_t t0 = min(28u * m0, m0 + 28u);
  uint32_t t1 = min(28u * m1, m1 + 28u);
  return (t0 << 9) | ((c0 & 8u) << 12)
       | (t1 << 25) | ((c1 & 8u) << 28);
}

// Packed dword (4 payload bytes = 8 fp4 along k) -> 8 f16, times f16 scale.
__device__ __forceinline__ half8 decode8p(uint32_t q, _Float16 s) {
  union { uint32_t u[4]; half8 h; } w;
  w.u[0] = dec2(q & 0xFFu);
  w.u[1] = dec2((q >> 8) & 0xFFu);
  w.u[2] = dec2((q >> 16) & 0xFFu);
  w.u[3] = dec2((q >> 24) & 0xFFu);
  half8 sv = {s, s, s, s, s, s, s, s};
  return w.h * sv;  // 4x v_pk_mul_f16
}

// out[m][n] = bias[n] (atomic-fallback path only)
__global__ void init_out_kernel(floatx4* __restrict__ out4,
                                const floatx4* __restrict__ bias4) {
  int idx = blockIdx.x * blockDim.x + threadIdx.x;
  out4[idx] = bias4[idx & (N_DIM / 4 - 1)];
}

// out = bias + sum over KS partial slabs
__global__ void reduce_kernel(const floatx4* __restrict__ part,
                              const floatx4* __restrict__ bias4,
                              floatx4* __restrict__ out4) {
  int idx = blockIdx.x * blockDim.x + threadIdx.x;   // [0, 65536)
  floatx4 acc = bias4[idx & (N_DIM / 4 - 1)];
#pragma unroll
  for (int s = 0; s < KS; ++s)
    acc += part[(size_t)s * (M_DIM * N_DIM / 4) + idx];
  out4[idx] = acc;
}

template <bool PARTIAL>
__global__ __launch_bounds__(256, 2) void fp4_linear_kernel(
    const float* __restrict__ inp,     // [32, 8192] f32
    const int4*  __restrict__ qw4,     // [N][1024] int4 view of [N, K/2] i32
    const float* __restrict__ scales,  // [8192, 512] f32
    const float* __restrict__ amaxp,   // [1]
    float* __restrict__ outp)          // PARTIAL: ws [KS][32][8192]; else out
{
  __shared__ uint32_t Qs[NPB * QROW];     // 33280 B (payload-packed nibbles)
  __shared__ _Float16 As[M_DIM * AROW];   // 33280 B
  __shared__ _Float16 Ss[NPB * SROW];     //  8704 B  -> 75264 B, 2 blk/CU

  const int t    = threadIdx.x;
  const int lane = t & 63;
  const int w    = t >> 6;
  const int ks   = blockIdx.x & (KS - 1);
  const int nb   = blockIdx.x >> 4;       // log2(KS)
  const int n0   = nb * NPB;
  const float amax = amaxp[0];

  // ---- Stage Q: 128 rows x 1 KB contiguous; repack 4 int32 -> 1 dword. ----
  // Wave w covers rows [w*32, w*32+32); one wave-instruction = one full row
  // window (64 lanes x 16 B = 1 KB contiguous). 4 batches of 8 rows keep
  // staging registers at 32 VGPR (no spill).
  {
    const int4* qbase = qw4 + (size_t)ks * (KCH / 8);  // window: ks*64 int4
    for (int g = 0; g < 4; ++g) {
      int4 tmp[8];
#pragma unroll
      for (int j = 0; j < 8; ++j) {
        const int r = w * 32 + g * 8 + j;
        tmp[j] = qbase[(size_t)(n0 + r) * QW_ROWI4 + lane];
      }
#pragma unroll
      for (int j = 0; j < 8; ++j) {
        const int r = w * 32 + g * 8 + j;
        uint32_t pk = ((uint32_t)tmp[j].x & 0xFFu)
                    | (((uint32_t)tmp[j].y & 0xFFu) << 8)
                    | (((uint32_t)tmp[j].z & 0xFFu) << 16)
                    | (((uint32_t)tmp[j].w & 0xFFu) << 24);
        Qs[r * QROW + lane] = pk;
      }
    }
  }

  // ---- Stage A: 32 rows x 512 f32 (2 KB contiguous each) -> f16. ----
  {
    for (int g = 0; g < 2; ++g) {
      floatx4 tmp[8];
#pragma unroll
      for (int j = 0; j < 4; ++j) {
        const int r = w * 8 + g * 4 + j;
        const floatx4* ab =
            reinterpret_cast<const floatx4*>(inp + (size_t)r * K_DIM + ks * KCH);
        tmp[2 * j]     = ab[lane];
        tmp[2 * j + 1] = ab[lane + 64];
      }
#pragma unroll
      for (int j = 0; j < 4; ++j) {
        const int r = w * 8 + g * 4 + j;
        floatx4 f0 = tmp[2 * j], f1 = tmp[2 * j + 1];
        half4_t h0, h1;
        h0[0] = (_Float16)f0[0]; h0[1] = (_Float16)f0[1];
        h0[2] = (_Float16)f0[2]; h0[3] = (_Float16)f0[3];
        h1[0] = (_Float16)f1[0]; h1[1] = (_Float16)f1[1];
        h1[2] = (_Float16)f1[2]; h1[3] = (_Float16)f1[3];
        *(half4_t*)&As[r * AROW + lane * 4]        = h0;
        *(half4_t*)&As[r * AROW + (lane + 64) * 4] = h1;
      }
    }
  }

  // ---- Stage scales: 128 rows x 32 f32 (128 B contiguous) -> f16 * amax. ----
  {
#pragma unroll
    for (int j = 0; j < 4; ++j) {
      const int idx = j * 256 + t;           // [0, 1024) floatx4
      const int r = idx >> 3, c = idx & 7;
      floatx4 f = reinterpret_cast<const floatx4*>(
          scales + (size_t)(n0 + r) * SC_ROW + ks * (KCH / 16))[c];
      half4_t h;
      h[0] = (_Float16)(f[0] * amax); h[1] = (_Float16)(f[1] * amax);
      h[2] = (_Float16)(f[2] * amax); h[3] = (_Float16)(f[3] * amax);
      *(half4_t*)&Ss[r * SROW + c * 4] = h;
    }
  }
  __syncthreads();

  // ---- Compute: 16 k-steps of 4 MFMAs, all operands from LDS. ----
  const int row  = lane & 15;   // n-within-tile (B) / m-within-tile (A)
  const int quad = lane >> 4;   // which 8 k's of the 32-k MFMA step
  const int nloc = w * 32;

  const uint32_t* qAp = &Qs[(nloc + row) * QROW];
  const uint32_t* qBp = &Qs[(nloc + 16 + row) * QROW];
  const _Float16* a0p = &As[row * AROW];
  const _Float16* a1p = &As[(row + 16) * AROW];
  const _Float16* sAp = &Ss[(nloc + row) * SROW];
  const _Float16* sBp = &Ss[(nloc + 16 + row) * SROW];

  floatx4 acc00 = {0.f, 0.f, 0.f, 0.f};
  floatx4 acc01 = {0.f, 0.f, 0.f, 0.f};
  floatx4 acc10 = {0.f, 0.f, 0.f, 0.f};
  floatx4 acc11 = {0.f, 0.f, 0.f, 0.f};

#pragma unroll
  for (int it = 0; it < STEPS; ++it) {
    const uint32_t qA = qAp[it * 4 + quad];
    const uint32_t qB = qBp[it * 4 + quad];
    const _Float16 sA = sAp[it * 2 + (quad >> 1)];
    const _Float16 sB = sBp[it * 2 + (quad >> 1)];
    half8 bA = decode8p(qA, sA);
    half8 bB = decode8p(qB, sB);
    half8 a0 = *(const half8*)(a0p + it * 32 + quad * 8);
    half8 a1 = *(const half8*)(a1p + it * 32 + quad * 8);
    acc00 = __builtin_amdgcn_mfma_f32_16x16x32_f16(a0, bA, acc00, 0, 0, 0);
    acc01 = __builtin_amdgcn_mfma_f32_16x16x32_f16(a0, bB, acc01, 0, 0, 0);
    acc10 = __builtin_amdgcn_mfma_f32_16x16x32_f16(a1, bA, acc10, 0, 0, 0);
    acc11 = __builtin_amdgcn_mfma_f32_16x16x32_f16(a1, bB, acc11, 0, 0, 0);
  }

  // ---- Epilogue. D layout: col(n)=lane&15, row(m)=quad*4+reg (verified). ----
  if (PARTIAL) {
    float* pb = outp + (size_t)ks * (M_DIM * N_DIM);
#pragma unroll
    for (int r = 0; r < 4; ++r) {
      const int m = quad * 4 + r;
      float* o0 = pb + (size_t)m * N_DIM + n0 + nloc;
      float* o1 = pb + (size_t)(m + 16) * N_DIM + n0 + nloc;
      o0[row]      = acc00[r];
      o0[16 + row] = acc01[r];
      o1[row]      = acc10[r];
      o1[16 + row] = acc11[r];
    }
  } else {
#pragma unroll
    for (int r = 0; r < 4; ++r) {
      const int m = quad * 4 + r;
      float* o0 = outp + (size_t)m * N_DIM + n0 + nloc;
      float* o1 = outp + (size_t)(m + 16) * N_DIM + n0 + nloc;
      unsafeAtomicAdd(o0 + row,      acc00[r]);
      unsafeAtomicAdd(o0 + 16 + row, acc01[r]);
      unsafeAtomicAdd(o1 + row,      acc10[r]);
      unsafeAtomicAdd(o1 + 16 + row, acc11[r]);
    }
  }
}

extern "C" void kernel_launch(void* const* d_in, const int* in_sizes, int n_in,
                              void* d_out, int out_size, void* d_ws, size_t ws_size,
                              hipStream_t stream) {
  const float* inp    = (const float*)d_in[0];
  const int4*  qw4    = (const int4*)d_in[1];
  const float* scales = (const float*)d_in[2];
  const float* amaxp  = (const float*)d_in[3];
  const float* bias   = (const float*)d_in[4];
  float* out = (float*)d_out;

  const size_t part_bytes = (size_t)KS * M_DIM * N_DIM * sizeof(float);  // 16.8 MB
  if (ws_size >= part_bytes) {
    float* part = (float*)d_ws;
    fp4_linear_kernel<true><<<MAIN_BLOCKS, 256, 0, stream>>>(
        inp, qw4, scales, amaxp, part);
    reduce_kernel<<<M_DIM * N_DIM / 4 / 256, 256, 0, stream>>>(
        (const floatx4*)part, (const floatx4*)bias, (floatx4*)out);
  } else {
    init_out_kernel<<<M_DIM * N_DIM / 4 / 256, 256, 0, stream>>>(
        (floatx4*)out, (const floatx4*)bias);
    fp4_linear_kernel<false><<<MAIN_BLOCKS, 256, 0, stream>>>(
        inp, qw4, scales, amaxp, out);
  }
}